// Round 2
// baseline (599.917 us; speedup 1.0000x reference)
//
#include <hip/hip_runtime.h>
#include <math.h>

#define Bb 256
#define Ss 512
#define Tt 20
#define Ee 25
#define Hh 128
#define SKIPn 64
#define H4n 512
#define BSn (Bb*Ss)
#define MG 4             // batch rows per scan block (replicated 4x in M)
#define HP 160           // h16 LDS row pitch in halves: 80 words == 16 mod 32 -> free 2-way
#define ZROWS 256        // rows per zxs block (= Bb: one t per block)
#define LOG2E 1.4426950408889634f

typedef _Float16 f16x8 __attribute__((ext_vector_type(8)));
typedef _Float16 f16x4 __attribute__((ext_vector_type(4)));
typedef float f32x4 __attribute__((ext_vector_type(4)));

__device__ __forceinline__ float rcpf(float x) { return __builtin_amdgcn_rcpf(x); }
__device__ __forceinline__ float exp2f_(float x) { return __builtin_amdgcn_exp2f(x); }

// Barrier that waits only on LDS ops (lgkmcnt(0)); leaves vmcnt in flight.
__device__ __forceinline__ void lgkm_barrier() {
    __asm__ __volatile__("" ::: "memory");
    __builtin_amdgcn_s_waitcnt(0xC07F);
    __builtin_amdgcn_s_barrier();
    __asm__ __volatile__("" ::: "memory");
}

// ---------------- Kernel 1: embedding mean-pool (fp16 out, [t][b][32]) + masks ----------------
__global__ void pool_kernel(const int* __restrict__ tags,
                            const float* __restrict__ table,
                            _Float16* __restrict__ gru16, float* __restrict__ maskf,
                            float* __restrict__ maskt) {
    int group = blockIdx.x * 8 + (threadIdx.x >> 5);
    int lane = threadIdx.x & 31;
    if (group >= BSn) return;
    int b = group >> 9;          // group = b*Ss + t
    int t = group & (Ss - 1);
    const int* tg = tags + (size_t)group * Tt;
    const int el = (lane < Ee) ? lane : (Ee - 1);   // lanes 25..31 read a valid dup

    int tagv[Tt];
#pragma unroll
    for (int tt = 0; tt < Tt; tt++) tagv[tt] = tg[tt];

    float vv[Tt];
#pragma unroll
    for (int tt = 0; tt < Tt; tt++)
        vv[tt] = table[(size_t)tagv[tt] * Ee + el];   // independent, unconditional

    float acc = 0.0f;
    int cnt = 0;
#pragma unroll
    for (int tt = 0; tt < Tt; tt++) {
        const bool nz = (tagv[tt] != 0);
        cnt += nz ? 1 : 0;
        acc += nz ? vv[tt] : 0.0f;
    }
    float scale = rcpf((float)(cnt > 0 ? cnt : 1));
    float v = (lane < Ee) ? acc * scale : 0.0f;
    gru16[((size_t)t * Bb + b) * 32 + lane] = (_Float16)v;
    if (lane == 0) {
        float m = (tagv[0] != 0) ? 1.0f : 0.0f;
        maskf[group] = m;                       // [b][t] for attn
        maskt[(size_t)t * Bb + b] = m;          // [t][b] for scan
    }
}

// ---------------- Kernel 1b: skips fp32 -> fp16; TR: [b][t][64] -> [t][b][64] ----------------
template<bool TR>
__global__ void __launch_bounds__(256)
cvt_kernel(const float* __restrict__ in, _Float16* __restrict__ out) {
    size_t id = (size_t)blockIdx.x * 256 + threadIdx.x;   // one per 8 halves
    if (TR) {
        size_t bt = id >> 3;
        const int c8 = (int)(id & 7);
        const int b = (int)(bt >> 9);
        const int t = (int)(bt & (Ss - 1));
        const float* ip = in + bt * SKIPn + c8 * 8;
        f32x4 a = *(const f32x4*)(ip);
        f32x4 bv = *(const f32x4*)(ip + 4);
        f16x8 o;
#pragma unroll
        for (int j = 0; j < 4; j++) { o[j] = (_Float16)a[j]; o[j + 4] = (_Float16)bv[j]; }
        *(f16x8*)(out + ((size_t)t * Bb + b) * SKIPn + c8 * 8) = o;
    } else {
        size_t i = id * 8;
        f32x4 a = *(const f32x4*)(in + i);
        f32x4 bv = *(const f32x4*)(in + i + 4);
        f16x8 o;
#pragma unroll
        for (int j = 0; j < 4; j++) { o[j] = (_Float16)a[j]; o[j + 4] = (_Float16)bv[j]; }
        *(f16x8*)(out + i) = o;
    }
}

// ---------------- Kernel 1c: zxs precompute: z_xs = gs[g]*(x@K + s@Sk + b) ----------------
// Rows are t-major (t*Bb + b). Chunk k covers local rows [0, CH*Bb) per dir:
//   fwd: global t in [CH*k, CH*k+CH)        -> global row = CH*k*Bb + local
//   bwd: global t in [Ss-CH*(k+1), Ss-CH*k) -> global row = (Ss-CH*(k+1))*Bb + local
// Output zbuf layout [dir][local_row][col][gate] fp16 (scan reads one f16x4/cell/step).
template<int CH>
__global__ void __launch_bounds__(512)
zxs_kernel(const _Float16* __restrict__ gru16, const _Float16* __restrict__ sk16,
           const float* __restrict__ Kf, const float* __restrict__ Skf, const float* __restrict__ bf,
           const float* __restrict__ Kb, const float* __restrict__ Skb, const float* __restrict__ bb,
           _Float16* __restrict__ zbuf, int k)
{
    const int tid = threadIdx.x;
    const int lane = tid & 63;
    const int w = tid >> 6;
    const int l16 = lane & 15;
    const int q = lane >> 4;
    const int dir = blockIdx.x & 1;
    const int rg = blockIdx.x >> 1;
    const size_t lrow0 = (size_t)rg * ZROWS;
    const size_t grow0 = ((size_t)(dir ? (Ss - CH * (k + 1)) : (CH * k)) * Bb) + lrow0;
    const int col = 16 * w + l16;

    const float* Kw = dir ? Kb : Kf;
    const float* Sw = dir ? Skb : Skf;
    const float* bw = dir ? bb : bf;
    const float gs[4] = {LOG2E, LOG2E, 2.0f * LOG2E, LOG2E};

    // B fragments (gate-interleaved + exp2-scaled): chunk0 = x (pad 25->32), chunks 1,2 = skips
    f16x8 bx[4], bs0[4], bs1[4];
#pragma unroll
    for (int g = 0; g < 4; g++) {
        const int n = g * Hh + col;
        f16x8 vx, v0, v1;
#pragma unroll
        for (int j = 0; j < 8; j++) {
            const int kk = 8 * q + j;
            vx[j] = (_Float16)(((kk < Ee) ? Kw[kk * H4n + n] : 0.0f) * gs[g]);
            v0[j] = (_Float16)(Sw[kk * H4n + n] * gs[g]);
            v1[j] = (_Float16)(Sw[(32 + kk) * H4n + n] * gs[g]);
        }
        bx[g] = vx; bs0[g] = v0; bs1[g] = v1;
    }
    float biasv[4];
#pragma unroll
    for (int g = 0; g < 4; g++) biasv[g] = bw[g * Hh + col] * gs[g];

    auto lda = [&](f16x8& ax, f16x8& a0, f16x8& a1, int ch) {
        const size_t r = grow0 + 16 * ch + l16;
        ax = *(const f16x8*)(gru16 + r * 32 + 8 * q);
        a0 = *(const f16x8*)(sk16 + r * SKIPn + 8 * q);
        a1 = *(const f16x8*)(sk16 + r * SKIPn + 32 + 8 * q);
    };

    f16x8 ax, a0, a1, nx, n0, n1;
    lda(ax, a0, a1, 0);
#pragma unroll 1
    for (int ch = 0; ch < ZROWS / 16; ch++) {
        const int chn = (ch + 1 < ZROWS / 16) ? ch + 1 : ch;
        lda(nx, n0, n1, chn);            // depth-1 prefetch
        f32x4 acc[4];
#pragma unroll
        for (int g = 0; g < 4; g++) {
            f32x4 a = {biasv[g], biasv[g], biasv[g], biasv[g]};
            acc[g] = a;
        }
#pragma unroll
        for (int g = 0; g < 4; g++)
            acc[g] = __builtin_amdgcn_mfma_f32_16x16x32_f16(ax, bx[g], acc[g], 0, 0, 0);
#pragma unroll
        for (int g = 0; g < 4; g++)
            acc[g] = __builtin_amdgcn_mfma_f32_16x16x32_f16(a0, bs0[g], acc[g], 0, 0, 0);
#pragma unroll
        for (int g = 0; g < 4; g++)
            acc[g] = __builtin_amdgcn_mfma_f32_16x16x32_f16(a1, bs1[g], acc[g], 0, 0, 0);

        // C row m = 4q + r -> local row lrow0 + 16ch + 4q + r; pack 4 gates -> 8B store
        _Float16* op = zbuf + (((size_t)dir * CH * Bb + lrow0 + 16 * ch + 4 * q) * 128 + col) * 4;
#pragma unroll
        for (int r = 0; r < 4; r++) {
            f16x4 o;
#pragma unroll
            for (int g = 0; g < 4; g++) o[g] = (_Float16)acc[g][r];
            *(f16x4*)(op + (size_t)r * 512) = o;
        }
        ax = nx; a0 = n0; a1 = n1;
    }
}

// ---------------- Kernel 2 (split): bidirectional LSTM scan, h@R only ----------------
// Grid = 128 blocks (2 dir x 64 batch-groups of 4), 512 threads = 8 waves.
// Per step per wave: 16 MFMAs (4 gates x 4 K-chunks of recurrent h@R).
// Chunk k processes CH steps; carry (h,c fp32) bounced through global between chunks.
template<int CH>
__global__ void __launch_bounds__(512)
__attribute__((amdgpu_waves_per_eu(2, 2)))
scan_split(const _Float16* __restrict__ zbuf, const float* __restrict__ maskt,
           const float* __restrict__ Rf, const float* __restrict__ Rb,
           _Float16* __restrict__ hs16, float* __restrict__ hfwd,
           float2* __restrict__ carry, int k)
{
    constexpr int NCH = Ss / CH;
    __shared__ __align__(16) _Float16 h16[2 * MG * HP];

    const int tid = threadIdx.x;
    const int lane = tid & 63;
    const int w = tid >> 6;
    const int l16 = lane & 15;
    const int q = lane >> 4;         // this thread's batch row (0..3)
    const int mb = l16 >> 2;         // A-fragment source batch row (replicated)
    const int bg = blockIdx.x & 63;
    const int dir = blockIdx.x >> 6;
    const int b0 = bg * MG;
    const int col = 16 * w + l16;    // this thread's h column

    const float* Rw = dir ? Rb : Rf;
    const float gs[4] = {LOG2E, LOG2E, 2.0f * LOG2E, LOG2E};

    // Recurrent B-fragments, gate-interleaved+scaled: hfr[kt][g][j] = gs[g]*R[32kt+8q+j][g*128+col]
    f16x8 hfr[4][4];
#pragma unroll
    for (int kt = 0; kt < 4; kt++) {
#pragma unroll
        for (int g = 0; g < 4; g++) {
            const int n = g * Hh + col;
            f16x8 v;
#pragma unroll
            for (int j = 0; j < 8; j++)
                v[j] = (_Float16)(Rw[(32 * kt + 8 * q + j) * H4n + n] * gs[g]);
            hfr[kt][g] = v;
        }
    }

    const int cid = (dir * Bb + b0 + q) * Hh + col;
    float c = 0.0f, h = 0.0f;
    if (k > 0) { float2 hc = carry[cid]; h = hc.x; c = hc.y; }

    // Seed parity-0 h buffer (every cell written exactly once; pads never read).
    h16[q * HP + col] = (_Float16)h;

    // zbuf pointer for this cell: [dir][t_local*Bb + b][col][4]
    const _Float16* zbase = zbuf + ((size_t)dir * CH * Bb + (size_t)(b0 + q)) * 512 + col * 4;

    // hs16 write pointer; global t0 for this chunk
    const int t0 = dir ? (Ss - 1 - CH * k) : (CH * k);
    _Float16* hsp = hs16 + ((size_t)(b0 + q) * Ss + t0) * (2 * Hh) + dir * Hh + col;
    const ptrdiff_t odelta = dir ? -(2 * Hh) : (2 * Hh);

    auto issue_z = [&](f16x4& z, int i) {
        const int ii = (i < CH) ? i : (CH - 1);
        const int tl = dir ? (CH - 1 - ii) : ii;     // local zbuf row block
        z = *(const f16x4*)(zbase + (size_t)tl * (Bb * 512));
    };
    auto issue_m = [&](float& mk, int i) {
        const int ii = (i < CH) ? i : (CH - 1);
        const int tg = dir ? (Ss - 1 - CH * k - ii) : (CH * k + ii);
        mk = maskt[(size_t)tg * Bb + b0 + q];
    };

    // 2-slot depth-2 prefetch
    f16x4 zA, zB;
    float mA, mB;
    issue_z(zA, 0); issue_m(mA, 0);
    issue_z(zB, 1); issue_m(mB, 1);
    __syncthreads();

    auto body = [&](int i, f16x4& zf4, float& mkv) {
        const _Float16* hb = h16 + (i & 1) * (MG * HP);
        const f16x8 ah0 = *(const f16x8*)(hb + mb * HP +  0 + 8 * q);
        const f16x8 ah1 = *(const f16x8*)(hb + mb * HP + 32 + 8 * q);
        const f16x8 ah2 = *(const f16x8*)(hb + mb * HP + 64 + 8 * q);
        const f16x8 ah3 = *(const f16x8*)(hb + mb * HP + 96 + 8 * q);

        f32x4 acc[4];
#pragma unroll
        for (int g = 0; g < 4; g++) {
            const float zv = (float)zf4[g];
            f32x4 a = {zv, zv, zv, zv};
            acc[g] = a;
        }
        // refill z for step i+2 AFTER consumption (no fragment copies)
        issue_z(zf4, i + 2);
#pragma unroll
        for (int g = 0; g < 4; g++) {
            acc[g] = __builtin_amdgcn_mfma_f32_16x16x32_f16(ah0, hfr[0][g], acc[g], 0, 0, 0);
            acc[g] = __builtin_amdgcn_mfma_f32_16x16x32_f16(ah1, hfr[1][g], acc[g], 0, 0, 0);
            acc[g] = __builtin_amdgcn_mfma_f32_16x16x32_f16(ah2, hfr[2][g], acc[g], 0, 0, 0);
            acc[g] = __builtin_amdgcn_mfma_f32_16x16x32_f16(ah3, hfr[3][g], acc[g], 0, 0, 0);
        }

        // ---- gates: 1 cell/thread (batch q, col)
        const float mk = mkv;
        issue_m(mkv, i + 2);
        const float zi = acc[0][0], zf = acc[1][0], zg = acc[2][0], zo = acc[3][0];
        const float ei = exp2f_(fminf(-zi, 88.0f));   // e^{-z_i}
        const float ef = exp2f_(fminf(-zf, 88.0f));
        const float eg = exp2f_(fminf(-zg, 88.0f));   // e^{-2 z_g}
        const float eo = exp2f_(fminf(-zo, 88.0f));
        const float pi = 1.0f + ei, pg = 1.0f + eg, pf = 1.0f + ef;
        const float p  = pi * pg;
        const float t1 = (1.0f - eg) * pf;
        const float cn = fmaf(c, p, t1) * rcpf(pf * p);
        const float ec = exp2f_(fminf(cn * (-2.0f * LOG2E), 88.0f));   // e^{-2 cn}
        const float hn = (1.0f - ec) * rcpf((1.0f + eo) * (1.0f + ec));
        const bool mm = (mk != 0.0f);
        c = mm ? cn : c;
        h = mm ? hn : h;

        _Float16* hw = h16 + ((i + 1) & 1) * (MG * HP);
        hw[q * HP + col] = (_Float16)h;
        *hsp = (_Float16)h;
        hsp += odelta;
        lgkm_barrier();
    };

#pragma unroll 1
    for (int i = 0; i < CH; i += 2) {
        body(i,     zA, mA);
        body(i + 1, zB, mB);
    }

    if (k + 1 < NCH) carry[cid] = make_float2(h, c);
    if (dir == 0 && k + 1 == NCH) hfwd[(size_t)(b0 + q) * Hh + col] = h;
}

// ---------------- Kernel 2 (fallback): proven fused scan (x/s/bias in-loop) ----------------
__global__ void __launch_bounds__(512)
__attribute__((amdgpu_waves_per_eu(2, 2)))
scan_fused(const _Float16* __restrict__ gru16, const _Float16* __restrict__ skips16,
           const float* __restrict__ maskt,
           const float* __restrict__ Kf, const float* __restrict__ Rf,
           const float* __restrict__ Skf, const float* __restrict__ bf,
           const float* __restrict__ Kb, const float* __restrict__ Rb,
           const float* __restrict__ Skb, const float* __restrict__ bb,
           _Float16* __restrict__ hs16, float* __restrict__ hfwd)
{
    __shared__ __align__(16) _Float16 h16[2 * MG * HP];

    const int tid = threadIdx.x;
    const int lane = tid & 63;
    const int w = tid >> 6;
    const int l16 = lane & 15;
    const int q = lane >> 4;
    const int mb = l16 >> 2;
    const int bg = blockIdx.x & 63;
    const int dir = blockIdx.x >> 6;
    const int b0 = bg * MG;
    const int col = 16 * w + l16;

    const float* Kw = dir ? Kb : Kf;
    const float* Rw = dir ? Rb : Rf;
    const float* Sw = dir ? Skb : Skf;
    const float* bw = dir ? bb : bf;

    const float gs[4] = {LOG2E, LOG2E, 2.0f * LOG2E, LOG2E};

    f16x8 bfr[7][4];
#pragma unroll
    for (int kt = 0; kt < 7; kt++) {
#pragma unroll
        for (int g = 0; g < 4; g++) {
            const int n = g * Hh + col;
            f16x8 v;
#pragma unroll
            for (int j = 0; j < 8; j++) {
                const int k = 32 * kt + 8 * q + j;
                float x;
                if (k < 32)        x = (k < Ee) ? Kw[k * H4n + n] : 0.0f;
                else if (k < 160)  x = Rw[(k - 32) * H4n + n];
                else               x = Sw[(k - 160) * H4n + n];
                v[j] = (_Float16)(x * gs[g]);
            }
            bfr[kt][g] = v;
        }
    }
    float biasv[4];
#pragma unroll
    for (int g = 0; g < 4; g++) biasv[g] = bw[g * Hh + col] * gs[g];

    for (int idx = tid; idx < 2 * MG * HP; idx += 512) h16[idx] = (_Float16)0.0f;

    const _Float16* srow = skips16 + (size_t)(b0 + mb) * Ss * SKIPn;
    float c = 0.0f, h = 0.0f;

    _Float16* hsp = hs16 + ((size_t)(b0 + q) * Ss + (dir ? Ss - 1 : 0)) * (2 * Hh)
                    + dir * Hh + col;
    const ptrdiff_t odelta = dir ? -(2 * Hh) : (2 * Hh);

    auto issue_xs = [&](f16x8& xf, f16x8& s0, f16x8& s1, int i) {
        const int ii = (i < Ss) ? i : (Ss - 1);
        const int t = dir ? (Ss - 1 - ii) : ii;
        xf = *(const f16x8*)(gru16 + ((size_t)t * Bb + b0 + mb) * 32 + 8 * q);
        const _Float16* sp = srow + (size_t)t * SKIPn;
        s0 = *(const f16x8*)(sp + 8 * q);
        s1 = *(const f16x8*)(sp + 32 + 8 * q);
    };
    auto issue_m = [&](float& mk, int i) {
        const int ii = (i < Ss) ? i : (Ss - 1);
        const int t = dir ? (Ss - 1 - ii) : ii;
        mk = maskt[(size_t)t * Bb + b0 + q];
    };

    f16x8 xA, xB, sA0, sA1, sB0, sB1;
    float mA, mB;
    issue_xs(xA, sA0, sA1, 0); issue_m(mA, 0);
    issue_xs(xB, sB0, sB1, 1); issue_m(mB, 1);
    __syncthreads();

    auto body = [&](int i, f16x8& xf, f16x8& s0, f16x8& s1, float& mkv) {
        const _Float16* hb = h16 + (i & 1) * (MG * HP);
        const f16x8 ah0 = *(const f16x8*)(hb + mb * HP +  0 + 8 * q);
        const f16x8 ah1 = *(const f16x8*)(hb + mb * HP + 32 + 8 * q);
        const f16x8 ah2 = *(const f16x8*)(hb + mb * HP + 64 + 8 * q);
        const f16x8 ah3 = *(const f16x8*)(hb + mb * HP + 96 + 8 * q);

        f32x4 acc[4];
#pragma unroll
        for (int g = 0; g < 4; g++) {
            f32x4 a = {biasv[g], biasv[g], biasv[g], biasv[g]};
            acc[g] = a;
        }
#pragma unroll
        for (int g = 0; g < 4; g++) {
            acc[g] = __builtin_amdgcn_mfma_f32_16x16x32_f16(xf, bfr[0][g], acc[g], 0, 0, 0);
            acc[g] = __builtin_amdgcn_mfma_f32_16x16x32_f16(s0, bfr[5][g], acc[g], 0, 0, 0);
            acc[g] = __builtin_amdgcn_mfma_f32_16x16x32_f16(s1, bfr[6][g], acc[g], 0, 0, 0);
        }
        issue_xs(xf, s0, s1, i + 2);
#pragma unroll
        for (int g = 0; g < 4; g++) {
            acc[g] = __builtin_amdgcn_mfma_f32_16x16x32_f16(ah0, bfr[1][g], acc[g], 0, 0, 0);
            acc[g] = __builtin_amdgcn_mfma_f32_16x16x32_f16(ah1, bfr[2][g], acc[g], 0, 0, 0);
            acc[g] = __builtin_amdgcn_mfma_f32_16x16x32_f16(ah2, bfr[3][g], acc[g], 0, 0, 0);
            acc[g] = __builtin_amdgcn_mfma_f32_16x16x32_f16(ah3, bfr[4][g], acc[g], 0, 0, 0);
        }

        const float mk = mkv;
        issue_m(mkv, i + 2);
        const float zi = acc[0][0], zf = acc[1][0], zg = acc[2][0], zo = acc[3][0];
        const float ei = exp2f_(fminf(-zi, 88.0f));
        const float ef = exp2f_(fminf(-zf, 88.0f));
        const float eg = exp2f_(fminf(-zg, 88.0f));
        const float eo = exp2f_(fminf(-zo, 88.0f));
        const float pi = 1.0f + ei, pg = 1.0f + eg, pf = 1.0f + ef;
        const float p  = pi * pg;
        const float t1 = (1.0f - eg) * pf;
        const float cn = fmaf(c, p, t1) * rcpf(pf * p);
        const float ec = exp2f_(fminf(cn * (-2.0f * LOG2E), 88.0f));
        const float hn = (1.0f - ec) * rcpf((1.0f + eo) * (1.0f + ec));
        const bool mm = (mk != 0.0f);
        c = mm ? cn : c;
        h = mm ? hn : h;

        _Float16* hw = h16 + ((i + 1) & 1) * (MG * HP);
        hw[q * HP + col] = (_Float16)h;
        *hsp = (_Float16)h;
        hsp += odelta;
        lgkm_barrier();
    };

#pragma unroll 1
    for (int i = 0; i < Ss; i += 2) {
        body(i,     xA, sA0, sA1, mA);
        body(i + 1, xB, sB0, sB1, mB);
    }

    if (dir == 0) hfwd[(size_t)(b0 + q) * Hh + col] = h;
}

// ---------------- Kernel 3: fused attention: q + energy + softmax + context ----------------
__global__ void __launch_bounds__(512)
attn_kernel(const _Float16* __restrict__ hs16, const float* __restrict__ hfwd,
            const float* __restrict__ Wq, const float* __restrict__ bq,
            const float* __restrict__ bk,
            const float* __restrict__ Wk, const float* __restrict__ We,
            const float* __restrict__ maskf, float* __restrict__ outp)
{
    __shared__ float hfl[Hh];
    __shared__ float qpart[4][Hh];
    __shared__ float qtot_s[Hh];
    __shared__ float epart[8][Ss];
    __shared__ float ws2[Ss];
    __shared__ float redm[8], reds[8];
    __shared__ float ctxp[16][2 * Hh + 1];

    const int tid = threadIdx.x;
    const int lane = tid & 63;
    const int w = tid >> 6;
    const int l16 = lane & 15;
    const int q = lane >> 4;
    const int b = blockIdx.x;
    const int j = 16 * w + l16;

    f16x8 bk16[8];
#pragma unroll
    for (int kt = 0; kt < 8; kt++) {
        f16x8 v;
#pragma unroll
        for (int jj = 0; jj < 8; jj++)
            v[jj] = (_Float16)Wk[(32 * kt + 8 * q + jj) * Hh + j];
        bk16[kt] = v;
    }
    const float wej = We[j];

    if (tid < Hh) hfl[tid] = hfwd[(size_t)b * Hh + tid];
    __syncthreads();
    {
        const int jj = tid & 127, seg = tid >> 7;
        float p = 0.0f;
#pragma unroll
        for (int k = 0; k < 32; k++)
            p += hfl[32 * seg + k] * Wq[(32 * seg + k) * Hh + jj];
        qpart[seg][jj] = p;
    }
    __syncthreads();
    if (tid < Hh)
        qtot_s[tid] = qpart[0][tid] + qpart[1][tid] + qpart[2][tid] + qpart[3][tid]
                      + bq[tid] + bk[tid];
    __syncthreads();
    const float qj = qtot_s[j];

    const _Float16* hb = hs16 + (size_t)b * Ss * (2 * Hh);
#pragma unroll 1
    for (int st = 0; st < 32; st++) {
        const int s0 = st * 16;
        const _Float16* arow = hb + (size_t)(s0 + l16) * (2 * Hh) + 8 * q;
        f32x4 acc = {0.f, 0.f, 0.f, 0.f};
#pragma unroll
        for (int kt = 0; kt < 8; kt++) {
            const f16x8 a = *(const f16x8*)(arow + 32 * kt);
            acc = __builtin_amdgcn_mfma_f32_16x16x32_f16(a, bk16[kt], acc, 0, 0, 0);
        }
        float vals[4];
#pragma unroll
        for (int r = 0; r < 4; r++) {
            const float x = acc[r] + qj;
            const float e = exp2f_(fminf(x * (-2.0f * LOG2E), 80.0f));
            vals[r] = (1.0f - e) * rcpf(1.0f + e) * wej;
        }
#pragma unroll
        for (int m = 1; m < 16; m <<= 1) {
#pragma unroll
            for (int r = 0; r < 4; r++) vals[r] += __shfl_xor(vals[r], m);
        }
        if (l16 == 0) {
#pragma unroll
            for (int r = 0; r < 4; r++) epart[w][s0 + 4 * q + r] = vals[r];
        }
    }
    __syncthreads();

    {
        float e = 0.0f;
#pragma unroll
        for (int ww = 0; ww < 8; ww++) e += epart[ww][tid];
        e += (1.0f - maskf[(size_t)b * Ss + tid]) * -1e9f;
        float mx = e;
#pragma unroll
        for (int off = 32; off > 0; off >>= 1) mx = fmaxf(mx, __shfl_xor(mx, off));
        if (lane == 0) redm[w] = mx;
        __syncthreads();
        mx = redm[0];
#pragma unroll
        for (int ww = 1; ww < 8; ww++) mx = fmaxf(mx, redm[ww]);
        const float p = exp2f_((e - mx) * LOG2E);
        float sm = p;
#pragma unroll
        for (int off = 32; off > 0; off >>= 1) sm += __shfl_xor(sm, off);
        if (lane == 0) reds[w] = sm;
        __syncthreads();
        sm = reds[0] + reds[1] + reds[2] + reds[3] + reds[4] + reds[5] + reds[6] + reds[7];
        ws2[(tid & 31) * 16 + (tid >> 5)] = p * rcpf(sm);
    }
    __syncthreads();

    {
        const int cg = tid >> 4;
        const int seg = tid & 15;
        float a[8];
#pragma unroll
        for (int jj = 0; jj < 8; jj++) a[jj] = 0.0f;
#pragma unroll 4
        for (int sg = 0; sg < 32; sg++) {
            const int s = seg * 32 + sg;
            const float wv = ws2[sg * 16 + seg];
            const f16x8 hv = *(const f16x8*)(hb + (size_t)s * (2 * Hh) + 8 * cg);
#pragma unroll
            for (int jj = 0; jj < 8; jj++) a[jj] = fmaf(wv, (float)hv[jj], a[jj]);
        }
#pragma unroll
        for (int jj = 0; jj < 8; jj++) ctxp[seg][8 * cg + jj] = a[jj];
    }
    __syncthreads();
    if (tid < 2 * Hh) {
        float s = 0.0f;
#pragma unroll
        for (int seg = 0; seg < 16; seg++) s += ctxp[seg][tid];
        outp[(size_t)b * (2 * Hh) + tid] = s;
    }
}

// ---------------- Launcher: pick path by ws_size ----------------
extern "C" void kernel_launch(void* const* d_in, const int* in_sizes, int n_in,
                              void* d_out, int out_size, void* d_ws, size_t ws_size,
                              hipStream_t stream) {
    const int*   tags  = (const int*)d_in[0];
    const float* skips = (const float*)d_in[1];
    const float* table = (const float*)d_in[2];
    const float* Kf    = (const float*)d_in[3];
    const float* Rf    = (const float*)d_in[4];
    const float* Skf   = (const float*)d_in[5];
    const float* bf    = (const float*)d_in[6];
    const float* Kb    = (const float*)d_in[7];
    const float* Rb    = (const float*)d_in[8];
    const float* Skb   = (const float*)d_in[9];
    const float* bb    = (const float*)d_in[10];
    const float* Wk    = (const float*)d_in[11];
    const float* bk    = (const float*)d_in[12];
    const float* Wq    = (const float*)d_in[13];
    const float* bq    = (const float*)d_in[14];
    const float* We    = (const float*)d_in[15];

    const size_t SZ_GRU = (size_t)BSn * 32 * 2;          // 8.4 MB
    const size_t SZ_SKT = (size_t)BSn * SKIPn * 2;       // 16.8 MB
    const size_t SZ_HS  = (size_t)BSn * 2 * Hh * 2;      // 67.1 MB
    const size_t SZ_MSK = (size_t)BSn * 4;               // 0.5 MB
    const size_t SZ_HF  = (size_t)Bb * Hh * 4;           // 0.13 MB
    const size_t SZ_CAR = (size_t)2 * Bb * Hh * 8;       // 0.5 MB
    const size_t SZ_ZF  = (size_t)2 * Ss * Bb * 512 * 2; // 268.4 MB (CH=512)
    const size_t SZ_ZC  = (size_t)2 * 128 * Bb * 512 * 2;// 67.1 MB  (CH=128)

    const size_t NEED_FULL  = SZ_ZF + SZ_HS + 2 * SZ_MSK + SZ_HF;
    const size_t NEED_CHUNK = SZ_ZC + SZ_GRU + SZ_SKT + SZ_HS + 2 * SZ_MSK + SZ_HF + SZ_CAR;

    char* ws = (char*)d_ws;

    if (ws_size >= NEED_FULL) {
        // ---- FULL: single zxs pass; gru16/sk16t overlaid in hs16 (dead before scan writes)
        _Float16* zbuf  = (_Float16*)ws; ws += SZ_ZF;
        _Float16* hs16  = (_Float16*)ws;
        _Float16* gru16 = (_Float16*)ws;
        _Float16* sk16t = (_Float16*)(ws + SZ_GRU);
        ws += SZ_HS;
        float* maskf = (float*)ws; ws += SZ_MSK;
        float* maskt = (float*)ws; ws += SZ_MSK;
        float* hfwd  = (float*)ws; ws += SZ_HF;

        pool_kernel<<<BSn / 8, 256, 0, stream>>>(tags, table, gru16, maskf, maskt);
        cvt_kernel<true><<<BSn * SKIPn / (256 * 8), 256, 0, stream>>>(skips, sk16t);
        zxs_kernel<Ss><<<2 * (Ss * Bb / ZROWS), 512, 0, stream>>>(
            gru16, sk16t, Kf, Skf, bf, Kb, Skb, bb, zbuf, 0);
        scan_split<Ss><<<128, 512, 0, stream>>>(zbuf, maskt, Rf, Rb, hs16, hfwd,
                                                (float2*)hfwd /*unused*/, 0);
        attn_kernel<<<Bb, 512, 0, stream>>>(hs16, hfwd, Wq, bq, bk, Wk, We, maskf,
                                            (float*)d_out);
    } else if (ws_size >= NEED_CHUNK) {
        // ---- CHUNK: 4 chunks of 128 steps; zbuf reused; carry bounced through global
        _Float16* zbuf  = (_Float16*)ws; ws += SZ_ZC;
        _Float16* gru16 = (_Float16*)ws; ws += SZ_GRU;
        _Float16* sk16t = (_Float16*)ws; ws += SZ_SKT;
        _Float16* hs16  = (_Float16*)ws; ws += SZ_HS;
        float* maskf = (float*)ws; ws += SZ_MSK;
        float* maskt = (float*)ws; ws += SZ_MSK;
        float* hfwd  = (float*)ws; ws += SZ_HF;
        float2* carry = (float2*)ws; ws += SZ_CAR;

        pool_kernel<<<BSn / 8, 256, 0, stream>>>(tags, table, gru16, maskf, maskt);
        cvt_kernel<true><<<BSn * SKIPn / (256 * 8), 256, 0, stream>>>(skips, sk16t);
        for (int k = 0; k < 4; k++) {
            zxs_kernel<128><<<2 * (128 * Bb / ZROWS), 512, 0, stream>>>(
                gru16, sk16t, Kf, Skf, bf, Kb, Skb, bb, zbuf, k);
            scan_split<128><<<128, 512, 0, stream>>>(zbuf, maskt, Rf, Rb, hs16, hfwd,
                                                     carry, k);
        }
        attn_kernel<<<Bb, 512, 0, stream>>>(hs16, hfwd, Wq, bq, bk, Wk, We, maskf,
                                            (float*)d_out);
    } else {
        // ---- FALLBACK: proven 93.4 MB layout + fused scan (551 us baseline)
        _Float16* gru16   = (_Float16*)ws; ws += SZ_GRU;
        _Float16* skips16 = (_Float16*)ws; ws += SZ_SKT;
        float* maskf = (float*)ws; ws += SZ_MSK;
        float* maskt = (float*)ws; ws += SZ_MSK;
        _Float16* hs16 = (_Float16*)ws; ws += SZ_HS;
        float* hfwd  = (float*)ws; ws += SZ_HF;

        pool_kernel<<<BSn / 8, 256, 0, stream>>>(tags, table, gru16, maskf, maskt);
        cvt_kernel<false><<<BSn * SKIPn / (256 * 8), 256, 0, stream>>>(skips, skips16);
        scan_fused<<<128, 512, 0, stream>>>(gru16, skips16, maskt,
                                            Kf, Rf, Skf, bf,
                                            Kb, Rb, Skb, bb,
                                            hs16, hfwd);
        attn_kernel<<<Bb, 512, 0, stream>>>(hs16, hfwd, Wq, bq, bk, Wk, We, maskf,
                                            (float*)d_out);
    }
}

// Round 3
// 539.724 us; speedup vs baseline: 1.1115x; 1.1115x over previous
//
#include <hip/hip_runtime.h>
#include <math.h>

#define Bb 256
#define Ss 512
#define Tt 20
#define Ee 25
#define Hh 128
#define SKIPn 64
#define H4n 512
#define BSn (Bb*Ss)
#define MG 4             // batch rows per scan block (replicated 4x in M)
#define HP 160           // h16 LDS row pitch in halves
#define ZP 520           // zlds row pitch in halves (512+8): q-groups 4 banks apart
#define AP 264           // attn atile pitch in halves: 16B-aligned, exactly-balanced banks
#define LOG2E 1.4426950408889634f

typedef _Float16 f16x8 __attribute__((ext_vector_type(8)));
typedef _Float16 f16x4 __attribute__((ext_vector_type(4)));
typedef float f32x4 __attribute__((ext_vector_type(4)));

__device__ __forceinline__ float rcpf(float x) { return __builtin_amdgcn_rcpf(x); }
__device__ __forceinline__ float exp2f_(float x) { return __builtin_amdgcn_exp2f(x); }

// Barrier that waits only on LDS ops (lgkmcnt(0)); leaves vmcnt in flight.
__device__ __forceinline__ void lgkm_barrier() {
    __asm__ __volatile__("" ::: "memory");
    __builtin_amdgcn_s_waitcnt(0xC07F);
    __builtin_amdgcn_s_barrier();
    __asm__ __volatile__("" ::: "memory");
}

// ---------------- Kernel 1: embedding mean-pool (fp16 out, [t][b][32]) + masks ----------------
__global__ void pool_kernel(const int* __restrict__ tags,
                            const float* __restrict__ table,
                            _Float16* __restrict__ gru16, float* __restrict__ maskf,
                            float* __restrict__ maskt) {
    int group = blockIdx.x * 8 + (threadIdx.x >> 5);
    int lane = threadIdx.x & 31;
    if (group >= BSn) return;
    int b = group >> 9;          // group = b*Ss + t
    int t = group & (Ss - 1);
    const int* tg = tags + (size_t)group * Tt;
    const int el = (lane < Ee) ? lane : (Ee - 1);   // lanes 25..31 read a valid dup

    int tagv[Tt];
#pragma unroll
    for (int tt = 0; tt < Tt; tt++) tagv[tt] = tg[tt];

    float vv[Tt];
#pragma unroll
    for (int tt = 0; tt < Tt; tt++)
        vv[tt] = table[(size_t)tagv[tt] * Ee + el];   // independent, unconditional

    float acc = 0.0f;
    int cnt = 0;
#pragma unroll
    for (int tt = 0; tt < Tt; tt++) {
        const bool nz = (tagv[tt] != 0);
        cnt += nz ? 1 : 0;
        acc += nz ? vv[tt] : 0.0f;
    }
    float scale = rcpf((float)(cnt > 0 ? cnt : 1));
    float v = (lane < Ee) ? acc * scale : 0.0f;
    gru16[((size_t)t * Bb + b) * 32 + lane] = (_Float16)v;
    if (lane == 0) {
        float m = (tagv[0] != 0) ? 1.0f : 0.0f;
        maskf[group] = m;                       // [b][t] for attn
        maskt[(size_t)t * Bb + b] = m;          // [t][b] for scan
    }
}

// ---------------- Kernel 1b: skips fp32 -> fp16 flat copy ([b][t][64]) ----------------
__global__ void __launch_bounds__(256)
cvt_kernel(const float* __restrict__ in, _Float16* __restrict__ out) {
    size_t i = ((size_t)blockIdx.x * 256 + threadIdx.x) * 8;
    f32x4 a = *(const f32x4*)(in + i);
    f32x4 b = *(const f32x4*)(in + i + 4);
    f16x8 o;
#pragma unroll
    for (int j = 0; j < 4; j++) { o[j] = (_Float16)a[j]; o[j + 4] = (_Float16)b[j]; }
    *(f16x8*)(out + i) = o;
}

// ---------------- Kernel 2: bidirectional LSTM scan, z_xs via in-kernel LDS GEMM phases ----------------
// Grid = 128 blocks (2 dir x 64 batch-groups of 4), 512 threads = 8 waves.
// Every 16 steps: GEMM phase computes z = gs*(x@K + s@Sk + b) for the next 16 steps of the
// block's 4 batches into zlds (replication-free: M-tile = 4 timesteps x 4 batches -> only
// 3 xs-MFMAs per wave per step amortized). Scan loop keeps only the 16 recurrent h@R MFMAs.
__global__ void __launch_bounds__(512)
__attribute__((amdgpu_waves_per_eu(2, 2)))
scan_kernel(const _Float16* __restrict__ gru16, const _Float16* __restrict__ sk16,
            const float* __restrict__ maskt,
            const float* __restrict__ Kf, const float* __restrict__ Rf,
            const float* __restrict__ Skf, const float* __restrict__ bf,
            const float* __restrict__ Kb, const float* __restrict__ Rb,
            const float* __restrict__ Skb, const float* __restrict__ bb,
            _Float16* __restrict__ hs16, float* __restrict__ hfwd)
{
    __shared__ __align__(16) _Float16 h16[2 * MG * HP];       // 2.5 KB
    __shared__ __align__(16) _Float16 zlds[64 * ZP];          // 66.6 KB: [tl*4+b][col][gate]

    const int tid = threadIdx.x;
    const int lane = tid & 63;
    const int w = tid >> 6;
    const int l16 = lane & 15;
    const int q = lane >> 4;         // this thread's batch row (0..3) in the scan
    const int mb = l16 >> 2;         // A-fragment source batch row (replicated, scan)
    const int bg = blockIdx.x & 63;
    const int dir = blockIdx.x >> 6;
    const int b0 = bg * MG;
    const int col = 16 * w + l16;    // this thread's h column

    const float* Kw = dir ? Kb : Kf;
    const float* Rw = dir ? Rb : Rf;
    const float* Sw = dir ? Skb : Skf;
    const float* bw = dir ? bb : bf;
    const float gs[4] = {LOG2E, LOG2E, 2.0f * LOG2E, LOG2E};

    // Recurrent B-fragments: hfr[kt][g][j] = gs[g]*R[32kt+8q+j][g*128+col]
    f16x8 hfr[4][4];
#pragma unroll
    for (int kt = 0; kt < 4; kt++) {
#pragma unroll
        for (int g = 0; g < 4; g++) {
            const int n = g * Hh + col;
            f16x8 v;
#pragma unroll
            for (int j = 0; j < 8; j++)
                v[j] = (_Float16)(Rw[(32 * kt + 8 * q + j) * H4n + n] * gs[g]);
            hfr[kt][g] = v;
        }
    }
    // GEMM-phase B-fragments (x pad 25->32, skips halves) + bias broadcast as MFMA C-input
    f16x8 bx[4], bs0[4], bs1[4];
    f32x4 biasA[4];
#pragma unroll
    for (int g = 0; g < 4; g++) {
        const int n = g * Hh + col;
        f16x8 vx, v0, v1;
#pragma unroll
        for (int j = 0; j < 8; j++) {
            const int kk = 8 * q + j;
            vx[j] = (_Float16)(((kk < Ee) ? Kw[kk * H4n + n] : 0.0f) * gs[g]);
            v0[j] = (_Float16)(Sw[kk * H4n + n] * gs[g]);
            v1[j] = (_Float16)(Sw[(32 + kk) * H4n + n] * gs[g]);
        }
        bx[g] = vx; bs0[g] = v0; bs1[g] = v1;
        const float bv = bw[g * Hh + col] * gs[g];
        f32x4 ba = {bv, bv, bv, bv};
        biasA[g] = ba;
    }
    const f32x4 zacc4 = {0.0f, 0.0f, 0.0f, 0.0f};   // persistent zero C-input

    for (int idx = tid; idx < 2 * MG * HP; idx += 512) h16[idx] = (_Float16)0.0f;

    float c = 0.0f, h = 0.0f;

    // GEMM A-row pointers: M-tile row m = 4*tsub + bb; lane l16 -> tsub=l16>>2, bb=l16&3.
    // Local step of lane's row in tile 'tile' of chunk k: 16k + 4*tile + tsub (scan order).
    const int tsub = l16 >> 2, bbn = l16 & 3;
    const int tg0 = dir ? (Ss - 1 - tsub) : tsub;
    const _Float16* px = gru16 + ((size_t)tg0 * Bb + b0 + bbn) * 32 + 8 * q;
    const _Float16* ps = sk16 + ((size_t)(b0 + bbn) * Ss + tg0) * SKIPn + 8 * q;
    const ptrdiff_t pxd = (dir ? -4 : 4) * (ptrdiff_t)(Bb * 32);
    const ptrdiff_t psd = (dir ? -4 : 4) * (ptrdiff_t)SKIPn;

    // mask running pointers (depth-2 prefetch; maskt has +-2 row padding)
    const float* mptr = maskt + (size_t)(dir ? (Ss - 1) : 0) * Bb + b0 + q;
    const ptrdiff_t mdelta = dir ? -(ptrdiff_t)Bb : (ptrdiff_t)Bb;
    float mA = mptr[0], mB = mptr[mdelta];
    const float* mpf = mptr + 2 * mdelta;

    // hs16 running write pointer
    _Float16* hsp = hs16 + ((size_t)(b0 + q) * Ss + (dir ? Ss - 1 : 0)) * (2 * Hh)
                    + dir * Hh + col;
    const ptrdiff_t odelta = dir ? -(2 * Hh) : (2 * Hh);

    // preload GEMM tile 0
    f16x8 nax = *(const f16x8*)px;
    f16x8 na0 = *(const f16x8*)ps;
    f16x8 na1 = *(const f16x8*)(ps + 32);

    __syncthreads();

    auto body = [&](int i, float& mkv) {
        const _Float16* hb = h16 + (i & 1) * (MG * HP);
        const f16x8 ah0 = *(const f16x8*)(hb + mb * HP +  0 + 8 * q);
        const f16x8 ah1 = *(const f16x8*)(hb + mb * HP + 32 + 8 * q);
        const f16x8 ah2 = *(const f16x8*)(hb + mb * HP + 64 + 8 * q);
        const f16x8 ah3 = *(const f16x8*)(hb + mb * HP + 96 + 8 * q);
        const f16x4 z4 = *(const f16x4*)(zlds + ((i & 15) * 4 + q) * ZP + col * 4);

        f32x4 acc[4];
#pragma unroll
        for (int g = 0; g < 4; g++) {
            acc[g] = __builtin_amdgcn_mfma_f32_16x16x32_f16(ah0, hfr[0][g], zacc4, 0, 0, 0);
            acc[g] = __builtin_amdgcn_mfma_f32_16x16x32_f16(ah1, hfr[1][g], acc[g], 0, 0, 0);
            acc[g] = __builtin_amdgcn_mfma_f32_16x16x32_f16(ah2, hfr[2][g], acc[g], 0, 0, 0);
            acc[g] = __builtin_amdgcn_mfma_f32_16x16x32_f16(ah3, hfr[3][g], acc[g], 0, 0, 0);
        }

        const float mk = mkv;
        mkv = *mpf; mpf += mdelta;
        const float zi = acc[0][0] + (float)z4[0];
        const float zf = acc[1][0] + (float)z4[1];
        const float zg = acc[2][0] + (float)z4[2];
        const float zo = acc[3][0] + (float)z4[3];
        const float ei = exp2f_(fminf(-zi, 88.0f));   // e^{-z_i}
        const float ef = exp2f_(fminf(-zf, 88.0f));
        const float eg = exp2f_(fminf(-zg, 88.0f));   // e^{-2 z_g}
        const float eo = exp2f_(fminf(-zo, 88.0f));
        const float pi = 1.0f + ei, pg = 1.0f + eg, pf = 1.0f + ef;
        const float p  = pi * pg;
        const float t1 = (1.0f - eg) * pf;
        const float cn = fmaf(c, p, t1) * rcpf(pf * p);
        const float ec = exp2f_(fminf(cn * (-2.0f * LOG2E), 88.0f));   // e^{-2 cn}
        const float hn = (1.0f - ec) * rcpf((1.0f + eo) * (1.0f + ec));
        const bool mm = (mk != 0.0f);
        c = mm ? cn : c;
        h = mm ? hn : h;

        _Float16* hw = h16 + ((i + 1) & 1) * (MG * HP);
        hw[q * HP + col] = (_Float16)h;
        *hsp = (_Float16)h;
        hsp += odelta;
        lgkm_barrier();
    };

    int i = 0;
#pragma unroll 1
    for (int k = 0; k < 32; ++k) {
        // ---- GEMM phase: z for the next 16 steps (4 M-tiles of 4t x 4b), depth-1 prefetch
#pragma unroll
        for (int tile = 0; tile < 4; ++tile) {
            const f16x8 ax = nax, a0 = na0, a1 = na1;
            px += pxd; ps += psd;
            if ((k < 31) | (tile < 3)) {
                nax = *(const f16x8*)px;
                na0 = *(const f16x8*)ps;
                na1 = *(const f16x8*)(ps + 32);
            }
            f32x4 zc[4];
#pragma unroll
            for (int g = 0; g < 4; g++) {
                zc[g] = __builtin_amdgcn_mfma_f32_16x16x32_f16(ax, bx[g],  biasA[g], 0, 0, 0);
                zc[g] = __builtin_amdgcn_mfma_f32_16x16x32_f16(a0, bs0[g], zc[g], 0, 0, 0);
                zc[g] = __builtin_amdgcn_mfma_f32_16x16x32_f16(a1, bs1[g], zc[g], 0, 0, 0);
            }
            // C row m = 4q + r -> tl = tile*4 + q, batch = r
            _Float16* zw = zlds + ((tile * 4 + q) * 4) * ZP + col * 4;
#pragma unroll
            for (int r = 0; r < 4; r++) {
                f16x4 o;
                o[0] = (_Float16)zc[0][r]; o[1] = (_Float16)zc[1][r];
                o[2] = (_Float16)zc[2][r]; o[3] = (_Float16)zc[3][r];
                *(f16x4*)(zw + r * ZP) = o;
            }
        }
        lgkm_barrier();
        // ---- scan span: 16 steps
#pragma unroll 1
        for (int j = 0; j < 16; j += 2) {
            body(i,     mA);
            body(i + 1, mB);
            i += 2;
        }
    }

    if (dir == 0) hfwd[(size_t)(b0 + q) * Hh + col] = h;
}

// ---------------- Kernel 3: fused attention: q + energy + softmax + context ----------------
// Phase 1: A-tiles staged through LDS (coalesced global reads, double-buffered).
// Phase 3: thread mapping swapped so 32 lanes read one contiguous 512 B row.
__global__ void __launch_bounds__(512)
attn_kernel(const _Float16* __restrict__ hs16, const float* __restrict__ hfwd,
            const float* __restrict__ Wq, const float* __restrict__ bq,
            const float* __restrict__ bk,
            const float* __restrict__ Wk, const float* __restrict__ We,
            const float* __restrict__ maskf, float* __restrict__ outp)
{
    __shared__ float hfl[Hh];
    __shared__ float qpart[4][Hh];
    __shared__ float qtot_s[Hh];
    __shared__ float epart[8][Ss];          // [wave][s]: conflict-free
    __shared__ float ws2[Ss];               // softmax weights, (s&31)*16+(s>>5)
    __shared__ float redm[8], reds[8];
    __shared__ float ctxp[16][2 * Hh + 1];  // pitch 257
    __shared__ __align__(16) _Float16 atile[2][16 * AP];   // 16.9 KB staging

    const int tid = threadIdx.x;
    const int lane = tid & 63;
    const int w = tid >> 6;
    const int l16 = lane & 15;
    const int q = lane >> 4;
    const int b = blockIdx.x;
    const int j = 16 * w + l16;

    // Wk B-fragments (K = 256): bk16[kt][jj] = Wk[32kt+8q+jj][j]
    f16x8 bk16[8];
#pragma unroll
    for (int kt = 0; kt < 8; kt++) {
        f16x8 v;
#pragma unroll
        for (int jj = 0; jj < 8; jj++)
            v[jj] = (_Float16)Wk[(32 * kt + 8 * q + jj) * Hh + j];
        bk16[kt] = v;
    }
    const float wej = We[j];

    // ---- phase 0: qtot = hfwd[b] @ Wq + bq + bk
    if (tid < Hh) hfl[tid] = hfwd[(size_t)b * Hh + tid];
    __syncthreads();
    {
        const int jj = tid & 127, seg = tid >> 7;
        float p = 0.0f;
#pragma unroll
        for (int k = 0; k < 32; k++)
            p += hfl[32 * seg + k] * Wq[(32 * seg + k) * Hh + jj];
        qpart[seg][jj] = p;
    }
    __syncthreads();
    if (tid < Hh)
        qtot_s[tid] = qpart[0][tid] + qpart[1][tid] + qpart[2][tid] + qpart[3][tid]
                      + bq[tid] + bk[tid];
    __syncthreads();
    const float qj = qtot_s[j];

    // ---- phase 1: energy via MFMA, LDS-staged A tiles
    const _Float16* hb = hs16 + (size_t)b * Ss * (2 * Hh);
    const int srow = tid >> 5;      // 0..15
    const int spart = tid & 31;     // 0..31
    *(f16x8*)(&atile[0][srow * AP + spart * 8]) =
        *(const f16x8*)(hb + (size_t)srow * (2 * Hh) + spart * 8);
    __syncthreads();
#pragma unroll 1
    for (int st = 0; st < 32; st++) {
        const int p = st & 1;
        f16x8 sreg;
        if (st < 31)
            sreg = *(const f16x8*)(hb + (size_t)((st + 1) * 16 + srow) * (2 * Hh) + spart * 8);
        const int s0 = st * 16;
        f32x4 acc = {0.f, 0.f, 0.f, 0.f};
#pragma unroll
        for (int kt = 0; kt < 8; kt++) {
            const f16x8 a = *(const f16x8*)(&atile[p][l16 * AP + kt * 32 + 8 * q]);
            acc = __builtin_amdgcn_mfma_f32_16x16x32_f16(a, bk16[kt], acc, 0, 0, 0);
        }
        float vals[4];
#pragma unroll
        for (int r = 0; r < 4; r++) {
            const float x = acc[r] + qj;
            const float e = exp2f_(fminf(x * (-2.0f * LOG2E), 80.0f));
            vals[r] = (1.0f - e) * rcpf(1.0f + e) * wej;   // tanh(x)*We[j]
        }
#pragma unroll
        for (int m = 1; m < 16; m <<= 1) {
#pragma unroll
            for (int r = 0; r < 4; r++) vals[r] += __shfl_xor(vals[r], m);
        }
        if (l16 == 0) {
#pragma unroll
            for (int r = 0; r < 4; r++) epart[w][s0 + 4 * q + r] = vals[r];
        }
        if (st < 31)
            *(f16x8*)(&atile[p ^ 1][srow * AP + spart * 8]) = sreg;
        __syncthreads();
    }

    // ---- phase 2: masked softmax over S (thread tid owns s=tid)
    {
        float e = 0.0f;
#pragma unroll
        for (int ww = 0; ww < 8; ww++) e += epart[ww][tid];
        e += (1.0f - maskf[(size_t)b * Ss + tid]) * -1e9f;
        float mx = e;
#pragma unroll
        for (int off = 32; off > 0; off >>= 1) mx = fmaxf(mx, __shfl_xor(mx, off));
        if (lane == 0) redm[w] = mx;
        __syncthreads();
        mx = redm[0];
#pragma unroll
        for (int ww = 1; ww < 8; ww++) mx = fmaxf(mx, redm[ww]);
        const float p = exp2f_((e - mx) * LOG2E);
        float sm = p;
#pragma unroll
        for (int off = 32; off > 0; off >>= 1) sm += __shfl_xor(sm, off);
        if (lane == 0) reds[w] = sm;
        __syncthreads();
        sm = reds[0] + reds[1] + reds[2] + reds[3] + reds[4] + reds[5] + reds[6] + reds[7];
        ws2[(tid & 31) * 16 + (tid >> 5)] = p * rcpf(sm);
    }
    __syncthreads();

    // ---- phase 3: context; cg = tid&31 -> 32 lanes read one contiguous row
    {
        const int cg = tid & 31;        // cols 8cg..8cg+7
        const int seg = tid >> 5;       // 0..15
        float a[8];
#pragma unroll
        for (int jj = 0; jj < 8; jj++) a[jj] = 0.0f;
#pragma unroll 4
        for (int sg = 0; sg < 32; sg++) {
            const int s = seg * 32 + sg;
            const float wv = ws2[sg * 16 + seg];
            const f16x8 hv = *(const f16x8*)(hb + (size_t)s * (2 * Hh) + 8 * cg);
#pragma unroll
            for (int jj = 0; jj < 8; jj++) a[jj] = fmaf(wv, (float)hv[jj], a[jj]);
        }
#pragma unroll
        for (int jj = 0; jj < 8; jj++) ctxp[seg][8 * cg + jj] = a[jj];
    }
    __syncthreads();
    if (tid < 2 * Hh) {
        float s = 0.0f;
#pragma unroll
        for (int seg = 0; seg < 16; seg++) s += ctxp[seg][tid];
        outp[(size_t)b * (2 * Hh) + tid] = s;
    }
}

// ---------------- Launcher ----------------
extern "C" void kernel_launch(void* const* d_in, const int* in_sizes, int n_in,
                              void* d_out, int out_size, void* d_ws, size_t ws_size,
                              hipStream_t stream) {
    const int*   tags  = (const int*)d_in[0];
    const float* skips = (const float*)d_in[1];
    const float* table = (const float*)d_in[2];
    const float* Kf    = (const float*)d_in[3];
    const float* Rf    = (const float*)d_in[4];
    const float* Skf   = (const float*)d_in[5];
    const float* bf    = (const float*)d_in[6];
    const float* Kb    = (const float*)d_in[7];
    const float* Rb    = (const float*)d_in[8];
    const float* Skb   = (const float*)d_in[9];
    const float* bb    = (const float*)d_in[10];
    const float* Wk    = (const float*)d_in[11];
    const float* bk    = (const float*)d_in[12];
    const float* Wq    = (const float*)d_in[13];
    const float* bq    = (const float*)d_in[14];
    const float* We    = (const float*)d_in[15];

    char* ws = (char*)d_ws;
    _Float16* gru16 = (_Float16*)ws; ws += (size_t)BSn * 32 * 2;        // 8.4 MB  [t][b][32]
    _Float16* sk16  = (_Float16*)ws; ws += (size_t)BSn * SKIPn * 2;     // 16.8 MB [b][t][64]
    float* maskf = (float*)ws; ws += (size_t)BSn * 4;                   // 0.5 MB  [b][t]
    float* maskt_base = (float*)ws; ws += ((size_t)BSn + 4 * Bb) * 4;   // 0.5 MB + pad
    float* maskt = maskt_base + 2 * Bb;                                 // +-2 row slack for prefetch
    _Float16* hs16 = (_Float16*)ws; ws += (size_t)BSn * 2 * Hh * 2;     // 67.1 MB
    float* hfwd  = (float*)ws; ws += (size_t)Bb * Hh * 4;               // total ~94 MB

    pool_kernel<<<BSn / 8, 256, 0, stream>>>(tags, table, gru16, maskf, maskt);
    cvt_kernel<<<BSn * SKIPn / (256 * 8), 256, 0, stream>>>(skips, sk16);
    scan_kernel<<<128, 512, 0, stream>>>(gru16, sk16, maskt,
                                         Kf, Rf, Skf, bf,
                                         Kb, Rb, Skb, bb,
                                         hs16, hfwd);
    attn_kernel<<<Bb, 512, 0, stream>>>(hs16, hfwd, Wq, bq, bk, Wk, We, maskf,
                                        (float*)d_out);
}

// Round 4
// 467.277 us; speedup vs baseline: 1.2839x; 1.1550x over previous
//
#include <hip/hip_runtime.h>
#include <math.h>

#define Bb 256
#define Ss 512
#define Tt 20
#define Ee 25
#define Hh 128
#define SKIPn 64
#define H4n 512
#define BSn (Bb*Ss)
#define MG 4             // batch rows per scan block (replicated 4x in M)
#define HP 160           // h16 LDS row pitch in halves
#define ZP 520           // zlds row pitch in halves (8B-aligned rows)
#define AP 264           // attn atile pitch in halves
#define LOG2E 1.4426950408889634f

typedef _Float16 f16x8 __attribute__((ext_vector_type(8)));
typedef _Float16 f16x4 __attribute__((ext_vector_type(4)));
typedef float f32x4 __attribute__((ext_vector_type(4)));

__device__ __forceinline__ float rcpf(float x) { return __builtin_amdgcn_rcpf(x); }
__device__ __forceinline__ float exp2f_(float x) { return __builtin_amdgcn_exp2f(x); }

// Barrier that waits only on LDS ops (lgkmcnt(0)); leaves vmcnt in flight.
__device__ __forceinline__ void lgkm_barrier() {
    __asm__ __volatile__("" ::: "memory");
    __builtin_amdgcn_s_waitcnt(0xC07F);
    __builtin_amdgcn_s_barrier();
    __asm__ __volatile__("" ::: "memory");
}

// ---------------- Kernel 1: embedding mean-pool (fp16 out, [t][b][32]) + masks ----------------
__global__ void pool_kernel(const int* __restrict__ tags,
                            const float* __restrict__ table,
                            _Float16* __restrict__ gru16, float* __restrict__ maskf,
                            float* __restrict__ maskt) {
    int group = blockIdx.x * 8 + (threadIdx.x >> 5);
    int lane = threadIdx.x & 31;
    if (group >= BSn) return;
    int b = group >> 9;          // group = b*Ss + t
    int t = group & (Ss - 1);
    const int* tg = tags + (size_t)group * Tt;
    const int el = (lane < Ee) ? lane : (Ee - 1);

    int tagv[Tt];
#pragma unroll
    for (int tt = 0; tt < Tt; tt++) tagv[tt] = tg[tt];

    float vv[Tt];
#pragma unroll
    for (int tt = 0; tt < Tt; tt++)
        vv[tt] = table[(size_t)tagv[tt] * Ee + el];

    float acc = 0.0f;
    int cnt = 0;
#pragma unroll
    for (int tt = 0; tt < Tt; tt++) {
        const bool nz = (tagv[tt] != 0);
        cnt += nz ? 1 : 0;
        acc += nz ? vv[tt] : 0.0f;
    }
    float scale = rcpf((float)(cnt > 0 ? cnt : 1));
    float v = (lane < Ee) ? acc * scale : 0.0f;
    gru16[((size_t)t * Bb + b) * 32 + lane] = (_Float16)v;
    if (lane == 0) {
        float m = (tagv[0] != 0) ? 1.0f : 0.0f;
        maskf[group] = m;                       // [b][t] for attn
        maskt[(size_t)t * Bb + b] = m;          // [t][b] for scan
    }
}

// ---------------- Kernel 1b: skips fp32 -> fp16 flat copy ([b][t][64]) ----------------
__global__ void __launch_bounds__(256)
cvt_kernel(const float* __restrict__ in, _Float16* __restrict__ out) {
    size_t i = ((size_t)blockIdx.x * 256 + threadIdx.x) * 8;
    f32x4 a = *(const f32x4*)(in + i);
    f32x4 b = *(const f32x4*)(in + i + 4);
    f16x8 o;
#pragma unroll
    for (int j = 0; j < 4; j++) { o[j] = (_Float16)a[j]; o[j + 4] = (_Float16)b[j]; }
    *(f16x8*)(out + i) = o;
}

// ---------------- Kernel 2: bidirectional LSTM scan; xs-GEMM dissolved into step bodies ----------------
// Grid = 128 blocks (2 dir x 64 batch-groups of 4), 512 threads = 8 waves.
// Per body: 16 recurrent h@R MFMAs (2-deep chains) + ~3 xs-GEMM MFMAs computing NEXT chunk's
// z into double-buffered zlds — the xs MFMAs + A-loads execute in the gate/barrier chain's shadow.
__global__ void __launch_bounds__(512)
__attribute__((amdgpu_waves_per_eu(2, 2)))
scan_kernel(const _Float16* __restrict__ gru16, const _Float16* __restrict__ sk16,
            const float* __restrict__ maskt,
            const float* __restrict__ Kf, const float* __restrict__ Rf,
            const float* __restrict__ Skf, const float* __restrict__ bf,
            const float* __restrict__ Kb, const float* __restrict__ Rb,
            const float* __restrict__ Skb, const float* __restrict__ bb,
            _Float16* __restrict__ hs16, float* __restrict__ hfwd)
{
    __shared__ __align__(16) _Float16 h16[2 * MG * HP];        // 2.5 KB
    __shared__ __align__(16) _Float16 zlds[2][16 * 4 * ZP];    // 130 KB double-buffered z

    const int tid = threadIdx.x;
    const int lane = tid & 63;
    const int w = tid >> 6;
    const int l16 = lane & 15;
    const int q = lane >> 4;         // this thread's batch row (0..3)
    const int mb = l16 >> 2;         // A-fragment source batch row (replicated)
    const int bg = blockIdx.x & 63;
    const int dir = blockIdx.x >> 6;
    const int b0 = bg * MG;
    const int col = 16 * w + l16;    // this thread's h column

    const float* Kw = dir ? Kb : Kf;
    const float* Rw = dir ? Rb : Rf;
    const float* Sw = dir ? Skb : Skf;
    const float* bw = dir ? bb : bf;
    const float gs[4] = {LOG2E, LOG2E, 2.0f * LOG2E, LOG2E};

    // Recurrent B-fragments: hfr[kt][g][j] = gs[g]*R[32kt+8q+j][g*128+col]
    f16x8 hfr[4][4];
#pragma unroll
    for (int kt = 0; kt < 4; kt++) {
#pragma unroll
        for (int g = 0; g < 4; g++) {
            const int n = g * Hh + col;
            f16x8 v;
#pragma unroll
            for (int j = 0; j < 8; j++)
                v[j] = (_Float16)(Rw[(32 * kt + 8 * q + j) * H4n + n] * gs[g]);
            hfr[kt][g] = v;
        }
    }
    // xs-GEMM B-fragments (x pad 25->32, skips halves) + bias as MFMA C-input
    f16x8 bx[4], bs0[4], bs1[4];
    f32x4 biasA[4];
#pragma unroll
    for (int g = 0; g < 4; g++) {
        const int n = g * Hh + col;
        f16x8 vx, v0, v1;
#pragma unroll
        for (int j = 0; j < 8; j++) {
            const int kk = 8 * q + j;
            vx[j] = (_Float16)(((kk < Ee) ? Kw[kk * H4n + n] : 0.0f) * gs[g]);
            v0[j] = (_Float16)(Sw[kk * H4n + n] * gs[g]);
            v1[j] = (_Float16)(Sw[(32 + kk) * H4n + n] * gs[g]);
        }
        bx[g] = vx; bs0[g] = v0; bs1[g] = v1;
        const float bv = bw[g * Hh + col] * gs[g];
        f32x4 ba = {bv, bv, bv, bv};
        biasA[g] = ba;
    }
    const f32x4 zacc4 = {0.0f, 0.0f, 0.0f, 0.0f};

    for (int idx = tid; idx < 2 * MG * HP; idx += 512) h16[idx] = (_Float16)0.0f;

    float c = 0.0f, h = 0.0f;

    // A-load pointers: uniform 4-timestep stream; M-row m = 4*tsub + bbn
    const int tsub = l16 >> 2, bbn = l16 & 3;
    const int tg0 = dir ? (Ss - 1 - tsub) : tsub;
    const _Float16* px = gru16 + ((size_t)tg0 * Bb + b0 + bbn) * 32 + 8 * q;
    const _Float16* ps = sk16 + ((size_t)(b0 + bbn) * Ss + tg0) * SKIPn + 8 * q;
    ptrdiff_t pxd = (dir ? -4 : 4) * (ptrdiff_t)(Bb * 32);
    ptrdiff_t psd = (dir ? -4 : 4) * (ptrdiff_t)SKIPn;

    // mask running prefetch (depth-2; maskt padded +-2 rows)
    const float* mpf = maskt + (size_t)(dir ? (Ss - 1) : 0) * Bb + b0 + q;
    const ptrdiff_t mdelta = dir ? -(ptrdiff_t)Bb : (ptrdiff_t)Bb;
    float mreg[2];
    mreg[0] = mpf[0]; mreg[1] = mpf[mdelta];
    mpf += 2 * mdelta;

    // hs16 running write pointer
    _Float16* hsp = hs16 + ((size_t)(b0 + q) * Ss + (dir ? Ss - 1 : 0)) * (2 * Hh)
                    + dir * Hh + col;
    const ptrdiff_t odelta = dir ? -(2 * Hh) : (2 * Hh);

    // A-tile load (consumes current pointers, then advances one tile = 4 timesteps)
    f16x8 gx, g0, g1;
    auto ldA = [&]() {
        gx = *(const f16x8*)px;
        g0 = *(const f16x8*)ps;
        g1 = *(const f16x8*)(ps + 32);
        px += pxd; ps += psd;
    };

    f32x4 zc[4];

    // ---- prologue: z(chunk 0) into zlds[0], serial (once)
    ldA();
#pragma unroll
    for (int T = 0; T < 4; T++) {
        const f16x8 ax = gx, a0 = g0, a1 = g1;
        ldA();
#pragma unroll
        for (int g = 0; g < 4; g++) {
            zc[g] = __builtin_amdgcn_mfma_f32_16x16x32_f16(ax, bx[g],  biasA[g], 0, 0, 0);
            zc[g] = __builtin_amdgcn_mfma_f32_16x16x32_f16(a0, bs0[g], zc[g], 0, 0, 0);
            zc[g] = __builtin_amdgcn_mfma_f32_16x16x32_f16(a1, bs1[g], zc[g], 0, 0, 0);
        }
        _Float16* zw = &zlds[0][0] + ((4 * T + q) * 4) * ZP + col * 4;
#pragma unroll
        for (int r = 0; r < 4; r++) {
            f16x4 o;
            o[0] = (_Float16)zc[0][r]; o[1] = (_Float16)zc[1][r];
            o[2] = (_Float16)zc[2][r]; o[3] = (_Float16)zc[3][r];
            *(f16x4*)(zw + r * ZP) = o;
        }
    }
    __syncthreads();

    // ---- main loop: chunk k runs steps 16k..16k+15, computes z(k+1) into the other buffer
#pragma unroll 1
    for (int k = 0; k < 32; ++k) {
        const _Float16* zr = &zlds[k & 1][0];
        _Float16* zwb = &zlds[(k + 1) & 1][0];

#pragma unroll
        for (int j = 0; j < 16; ++j) {
            const int T = j >> 2, ph = j & 3;

            // --- recurrent part (2-deep MFMA chains)
            const _Float16* hb = h16 + (j & 1) * (MG * HP);
            const f16x8 ah0 = *(const f16x8*)(hb + mb * HP +  0 + 8 * q);
            const f16x8 ah1 = *(const f16x8*)(hb + mb * HP + 32 + 8 * q);
            const f16x8 ah2 = *(const f16x8*)(hb + mb * HP + 64 + 8 * q);
            const f16x8 ah3 = *(const f16x8*)(hb + mb * HP + 96 + 8 * q);
            const f16x4 z4 = *(const f16x4*)(zr + (j * 4 + q) * ZP + col * 4);

            f32x4 accA[4], accB[4];
#pragma unroll
            for (int g = 0; g < 4; g++) {
                accA[g] = __builtin_amdgcn_mfma_f32_16x16x32_f16(ah0, hfr[0][g], zacc4, 0, 0, 0);
                accB[g] = __builtin_amdgcn_mfma_f32_16x16x32_f16(ah1, hfr[1][g], zacc4, 0, 0, 0);
                accA[g] = __builtin_amdgcn_mfma_f32_16x16x32_f16(ah2, hfr[2][g], accA[g], 0, 0, 0);
                accB[g] = __builtin_amdgcn_mfma_f32_16x16x32_f16(ah3, hfr[3][g], accB[g], 0, 0, 0);
            }

            // --- xs-GEMM interleave for z(k+1): rides the matrix pipe in the gate chain's shadow
            if (ph == 0) {
#pragma unroll
                for (int g = 0; g < 4; g++)
                    zc[g] = __builtin_amdgcn_mfma_f32_16x16x32_f16(gx, bx[g], biasA[g], 0, 0, 0);
            } else if (ph == 1) {
#pragma unroll
                for (int g = 0; g < 4; g++)
                    zc[g] = __builtin_amdgcn_mfma_f32_16x16x32_f16(g0, bs0[g], zc[g], 0, 0, 0);
            } else if (ph == 2) {
#pragma unroll
                for (int g = 0; g < 4; g++)
                    zc[g] = __builtin_amdgcn_mfma_f32_16x16x32_f16(g1, bs1[g], zc[g], 0, 0, 0);
                // freeze the A-stream before it would run past t=511 (chunk30's last ldA
                // and all of chunk31 would otherwise load t>=512)
                if (j == 10 && k == 30) { pxd = 0; psd = 0; }
                ldA();   // tile T+1 (continuous 4-timestep stream across chunks)
            } else {
                _Float16* zw = zwb + ((4 * T + q) * 4) * ZP + col * 4;
#pragma unroll
                for (int r = 0; r < 4; r++) {
                    f16x4 o;
                    o[0] = (_Float16)zc[0][r]; o[1] = (_Float16)zc[1][r];
                    o[2] = (_Float16)zc[2][r]; o[3] = (_Float16)zc[3][r];
                    *(f16x4*)(zw + r * ZP) = o;
                }
            }

            // --- gates (1 cell/thread); no clamps needed (|exp2 args| << 127)
            const float mk = mreg[j & 1];
            mreg[j & 1] = *mpf; mpf += mdelta;
            const float zi = accA[0][0] + accB[0][0] + (float)z4[0];
            const float zf = accA[1][0] + accB[1][0] + (float)z4[1];
            const float zg = accA[2][0] + accB[2][0] + (float)z4[2];
            const float zo = accA[3][0] + accB[3][0] + (float)z4[3];
            const float ei = exp2f_(-zi);            // e^{-z_i}
            const float ef = exp2f_(-zf);
            const float eg = exp2f_(-zg);            // e^{-2 z_g}
            const float eo = exp2f_(-zo);
            const float pi = 1.0f + ei, pg = 1.0f + eg, pf = 1.0f + ef;
            const float p  = pi * pg;
            const float t1 = (1.0f - eg) * pf;
            const float cn = fmaf(c, p, t1) * rcpf(pf * p);
            const float ec = exp2f_(cn * (-2.0f * LOG2E));   // e^{-2 cn}
            const float hn = (1.0f - ec) * rcpf((1.0f + eo) * (1.0f + ec));
            const bool mm = (mk != 0.0f);
            c = mm ? cn : c;
            h = mm ? hn : h;

            _Float16* hw = h16 + ((j + 1) & 1) * (MG * HP);
            hw[q * HP + col] = (_Float16)h;
            *hsp = (_Float16)h;
            hsp += odelta;
            lgkm_barrier();
        }
    }

    if (dir == 0) hfwd[(size_t)(b0 + q) * Hh + col] = h;
}

// ---------------- Kernel 3: fused attention: q + energy + softmax + context ----------------
__global__ void __launch_bounds__(512)
attn_kernel(const _Float16* __restrict__ hs16, const float* __restrict__ hfwd,
            const float* __restrict__ Wq, const float* __restrict__ bq,
            const float* __restrict__ bk,
            const float* __restrict__ Wk, const float* __restrict__ We,
            const float* __restrict__ maskf, float* __restrict__ outp)
{
    __shared__ float hfl[Hh];
    __shared__ float qpart[4][Hh];
    __shared__ float qtot_s[Hh];
    __shared__ float epart[8][Ss];
    __shared__ float ws2[Ss];
    __shared__ float redm[8], reds[8];
    __shared__ float ctxp[16][2 * Hh + 1];
    __shared__ __align__(16) _Float16 atile[2][16 * AP];

    const int tid = threadIdx.x;
    const int lane = tid & 63;
    const int w = tid >> 6;
    const int l16 = lane & 15;
    const int q = lane >> 4;
    const int b = blockIdx.x;
    const int j = 16 * w + l16;

    f16x8 bk16[8];
#pragma unroll
    for (int kt = 0; kt < 8; kt++) {
        f16x8 v;
#pragma unroll
        for (int jj = 0; jj < 8; jj++)
            v[jj] = (_Float16)Wk[(32 * kt + 8 * q + jj) * Hh + j];
        bk16[kt] = v;
    }
    const float wej = We[j];

    if (tid < Hh) hfl[tid] = hfwd[(size_t)b * Hh + tid];
    __syncthreads();
    {
        const int jj = tid & 127, seg = tid >> 7;
        float p = 0.0f;
#pragma unroll
        for (int k = 0; k < 32; k++)
            p += hfl[32 * seg + k] * Wq[(32 * seg + k) * Hh + jj];
        qpart[seg][jj] = p;
    }
    __syncthreads();
    if (tid < Hh)
        qtot_s[tid] = qpart[0][tid] + qpart[1][tid] + qpart[2][tid] + qpart[3][tid]
                      + bq[tid] + bk[tid];
    __syncthreads();
    const float qj = qtot_s[j];

    const _Float16* hb = hs16 + (size_t)b * Ss * (2 * Hh);
    const int srow = tid >> 5;
    const int spart = tid & 31;
    *(f16x8*)(&atile[0][srow * AP + spart * 8]) =
        *(const f16x8*)(hb + (size_t)srow * (2 * Hh) + spart * 8);
    __syncthreads();
#pragma unroll 1
    for (int st = 0; st < 32; st++) {
        const int p = st & 1;
        f16x8 sreg;
        if (st < 31)
            sreg = *(const f16x8*)(hb + (size_t)((st + 1) * 16 + srow) * (2 * Hh) + spart * 8);
        const int s0 = st * 16;
        f32x4 acc = {0.f, 0.f, 0.f, 0.f};
#pragma unroll
        for (int kt = 0; kt < 8; kt++) {
            const f16x8 a = *(const f16x8*)(&atile[p][l16 * AP + kt * 32 + 8 * q]);
            acc = __builtin_amdgcn_mfma_f32_16x16x32_f16(a, bk16[kt], acc, 0, 0, 0);
        }
        float vals[4];
#pragma unroll
        for (int r = 0; r < 4; r++) {
            const float x = acc[r] + qj;
            const float e = exp2f_(fminf(x * (-2.0f * LOG2E), 80.0f));
            vals[r] = (1.0f - e) * rcpf(1.0f + e) * wej;
        }
#pragma unroll
        for (int m = 1; m < 16; m <<= 1) {
#pragma unroll
            for (int r = 0; r < 4; r++) vals[r] += __shfl_xor(vals[r], m);
        }
        if (l16 == 0) {
#pragma unroll
            for (int r = 0; r < 4; r++) epart[w][s0 + 4 * q + r] = vals[r];
        }
        if (st < 31)
            *(f16x8*)(&atile[p ^ 1][srow * AP + spart * 8]) = sreg;
        __syncthreads();
    }

    {
        float e = 0.0f;
#pragma unroll
        for (int ww = 0; ww < 8; ww++) e += epart[ww][tid];
        e += (1.0f - maskf[(size_t)b * Ss + tid]) * -1e9f;
        float mx = e;
#pragma unroll
        for (int off = 32; off > 0; off >>= 1) mx = fmaxf(mx, __shfl_xor(mx, off));
        if (lane == 0) redm[w] = mx;
        __syncthreads();
        mx = redm[0];
#pragma unroll
        for (int ww = 1; ww < 8; ww++) mx = fmaxf(mx, redm[ww]);
        const float p = exp2f_((e - mx) * LOG2E);
        float sm = p;
#pragma unroll
        for (int off = 32; off > 0; off >>= 1) sm += __shfl_xor(sm, off);
        if (lane == 0) reds[w] = sm;
        __syncthreads();
        sm = reds[0] + reds[1] + reds[2] + reds[3] + reds[4] + reds[5] + reds[6] + reds[7];
        ws2[(tid & 31) * 16 + (tid >> 5)] = p * rcpf(sm);
    }
    __syncthreads();

    {
        const int cg = tid & 31;
        const int seg = tid >> 5;
        float a[8];
#pragma unroll
        for (int jj = 0; jj < 8; jj++) a[jj] = 0.0f;
#pragma unroll 4
        for (int sg = 0; sg < 32; sg++) {
            const int s = seg * 32 + sg;
            const float wv = ws2[sg * 16 + seg];
            const f16x8 hv = *(const f16x8*)(hb + (size_t)s * (2 * Hh) + 8 * cg);
#pragma unroll
            for (int jj = 0; jj < 8; jj++) a[jj] = fmaf(wv, (float)hv[jj], a[jj]);
        }
#pragma unroll
        for (int jj = 0; jj < 8; jj++) ctxp[seg][8 * cg + jj] = a[jj];
    }
    __syncthreads();
    if (tid < 2 * Hh) {
        float s = 0.0f;
#pragma unroll
        for (int seg = 0; seg < 16; seg++) s += ctxp[seg][tid];
        outp[(size_t)b * (2 * Hh) + tid] = s;
    }
}

// ---------------- Launcher ----------------
extern "C" void kernel_launch(void* const* d_in, const int* in_sizes, int n_in,
                              void* d_out, int out_size, void* d_ws, size_t ws_size,
                              hipStream_t stream) {
    const int*   tags  = (const int*)d_in[0];
    const float* skips = (const float*)d_in[1];
    const float* table = (const float*)d_in[2];
    const float* Kf    = (const float*)d_in[3];
    const float* Rf    = (const float*)d_in[4];
    const float* Skf   = (const float*)d_in[5];
    const float* bf    = (const float*)d_in[6];
    const float* Kb    = (const float*)d_in[7];
    const float* Rb    = (const float*)d_in[8];
    const float* Skb   = (const float*)d_in[9];
    const float* bb    = (const float*)d_in[10];
    const float* Wk    = (const float*)d_in[11];
    const float* bk    = (const float*)d_in[12];
    const float* Wq    = (const float*)d_in[13];
    const float* bq    = (const float*)d_in[14];
    const float* We    = (const float*)d_in[15];

    char* ws = (char*)d_ws;
    _Float16* gru16 = (_Float16*)ws; ws += (size_t)BSn * 32 * 2;        // 8.4 MB  [t][b][32]
    _Float16* sk16  = (_Float16*)ws; ws += (size_t)BSn * SKIPn * 2;     // 16.8 MB [b][t][64]
    float* maskf = (float*)ws; ws += (size_t)BSn * 4;                   // 0.5 MB  [b][t]
    float* maskt_base = (float*)ws; ws += ((size_t)BSn + 4 * Bb) * 4;   // 0.5 MB + pad
    float* maskt = maskt_base + 2 * Bb;                                 // +-2 row slack
    _Float16* hs16 = (_Float16*)ws; ws += (size_t)BSn * 2 * Hh * 2;     // 67.1 MB
    float* hfwd  = (float*)ws; ws += (size_t)Bb * Hh * 4;               // total ~94 MB

    pool_kernel<<<BSn / 8, 256, 0, stream>>>(tags, table, gru16, maskf, maskt);
    cvt_kernel<<<BSn * SKIPn / (256 * 8), 256, 0, stream>>>(skips, sk16);
    scan_kernel<<<128, 512, 0, stream>>>(gru16, sk16, maskt,
                                         Kf, Rf, Skf, bf,
                                         Kb, Rb, Skb, bb,
                                         hs16, hfwd);
    attn_kernel<<<Bb, 512, 0, stream>>>(hs16, hfwd, Wq, bq, bk, Wk, We, maskf,
                                        (float*)d_out);
}